// Round 1
// baseline (4375.900 us; speedup 1.0000x reference)
//
#include <hip/hip_runtime.h>
#include <hip/hip_bf16.h>
#include <math.h>

#define DIM 512
#define DEPTH 4
#define VOCAB 32000
#define HEADS 512
#define FF_DIM 2048
#define NB 2
#define NN 1024
#define M_TOK (NB * NN)   // 2048 token rows

// ---------------------------------------------------------------------------
// Embedding gather: x[t,:] = emb[tokens[t],:]
// ---------------------------------------------------------------------------
__global__ void gather_embed(const int* __restrict__ tok,
                             const float* __restrict__ emb,
                             float* __restrict__ x) {
    int t = blockIdx.x;               // 0..2047
    int c = threadIdx.x;              // 0..127 (float4 lanes)
    const float4* src = (const float4*)(emb + (size_t)tok[t] * DIM);
    float4* dst = (float4*)(x + (size_t)t * DIM);
    dst[c] = src[c];
}

// ---------------------------------------------------------------------------
// rmsnorm (reference: x / max(||x||,1e-12) * sqrt(DIM) * gamma)
// one wave (64 lanes) per row of 512 floats
// ---------------------------------------------------------------------------
__global__ void rmsnorm_k(const float* __restrict__ x,
                          const float* __restrict__ gamma,
                          float* __restrict__ y) {
    int wave = threadIdx.x >> 6;
    int lane = threadIdx.x & 63;
    int row  = blockIdx.x * 4 + wave;       // 2048 rows / 4 waves per block
    const float* xr = x + (size_t)row * DIM;
    float vals[8];
    float ss = 0.f;
#pragma unroll
    for (int i = 0; i < 8; i++) {
        vals[i] = xr[lane + i * 64];
        ss += vals[i] * vals[i];
    }
#pragma unroll
    for (int o = 32; o; o >>= 1) ss += __shfl_xor(ss, o, 64);
    float norm  = sqrtf(ss);
    float scale = 22.62741699796952f / fmaxf(norm, 1e-12f);  // sqrt(512)
    float* yr = y + (size_t)row * DIM;
#pragma unroll
    for (int i = 0; i < 8; i++) {
        int c = lane + i * 64;
        yr[c] = vals[i] * scale * gamma[c];
    }
}

// ---------------------------------------------------------------------------
// FP32 SGEMM: C[M,N] = act(A[M,K] @ W[K,N] + bias) + resid
// 64x64 tile, BK=16, 256 threads, 4x4 per thread.
// ACT: 0 = none, 1 = exact gelu, 2 = silu
// ---------------------------------------------------------------------------
__device__ __forceinline__ float gelu_f(float v) {
    return 0.5f * v * (1.f + erff(v * 0.7071067811865476f));
}
__device__ __forceinline__ float silu_f(float v) {
    return v / (1.f + __expf(-v));
}

template <int ACT>
__global__ __launch_bounds__(256)
void sgemm(const float* __restrict__ A, const float* __restrict__ W,
           const float* __restrict__ bias, const float* __restrict__ resid,
           float* __restrict__ C, int M, int N, int K) {
    __shared__ float As[16][68];   // [k][m], padded
    __shared__ float Bs[16][68];   // [k][n], padded
    const int bm = blockIdx.y * 64, bn = blockIdx.x * 64;
    const int tid = threadIdx.x;
    const int tx = tid & 15, ty = tid >> 4;
    const int ar = tid >> 2, ac = (tid & 3) << 2;   // A-tile row 0..63, col 0..12
    const int br = tid >> 4, bc = (tid & 15) << 2;  // B-tile row 0..15, col 0..60

    const float* Aptr = A + (size_t)(bm + ar) * K + ac;
    const float* Wptr = W + (size_t)br * N + bn + bc;

    float acc[4][4] = {};
    for (int k0 = 0; k0 < K; k0 += 16) {
        float4 av = *(const float4*)(Aptr + k0);
        float4 wv = *(const float4*)(Wptr + (size_t)k0 * N);
        __syncthreads();
        As[ac + 0][ar] = av.x;
        As[ac + 1][ar] = av.y;
        As[ac + 2][ar] = av.z;
        As[ac + 3][ar] = av.w;
        *(float4*)&Bs[br][bc] = wv;
        __syncthreads();
#pragma unroll
        for (int kk = 0; kk < 16; kk++) {
            float4 a4 = *(const float4*)&As[kk][ty << 2];
            float4 b4 = *(const float4*)&Bs[kk][tx << 2];
            float a[4] = {a4.x, a4.y, a4.z, a4.w};
            float b[4] = {b4.x, b4.y, b4.z, b4.w};
#pragma unroll
            for (int i = 0; i < 4; i++)
#pragma unroll
                for (int j = 0; j < 4; j++)
                    acc[i][j] = fmaf(a[i], b[j], acc[i][j]);
        }
    }
#pragma unroll
    for (int i = 0; i < 4; i++) {
        int m = bm + (ty << 2) + i;
        int n0 = bn + (tx << 2);
        float4 v;
        float* vp = (float*)&v;
#pragma unroll
        for (int j = 0; j < 4; j++) {
            float t = acc[i][j];
            if (bias) t += bias[n0 + j];
            if (ACT == 1) t = gelu_f(t);
            else if (ACT == 2) t = silu_f(t);
            if (resid) t += resid[(size_t)m * N + n0 + j];
            vp[j] = t;
        }
        *(float4*)&C[(size_t)m * N + n0] = v;
    }
}

// ---------------------------------------------------------------------------
// Gate-loop scan: one thread per (b, head). DH=1 so state is a complex scalar.
// qkv: [2048, 1536] (q|k|v each 512), abuf: [2048, 1024] ((re,im) per head),
// out: [2048, 512]
// ---------------------------------------------------------------------------
__global__ void scan_attn(const float* __restrict__ qkv,
                          const float* __restrict__ abuf,
                          float* __restrict__ out) {
    int t = blockIdx.x * 64 + threadIdx.x;   // 0..1023
    int b = t >> 9, h = t & 511;
    const float* qk = qkv + (size_t)b * NN * 1536;
    const float* ap = abuf + (size_t)b * NN * 1024;
    float* op = out + (size_t)b * NN * 512;
    float sr = 0.f, si = 0.f;
#pragma unroll 4
    for (int n = 0; n < NN; n++) {
        float q  = qk[(size_t)n * 1536 + h];
        float k  = qk[(size_t)n * 1536 + 512 + h];
        float v  = qk[(size_t)n * 1536 + 1024 + h];
        float re = ap[(size_t)n * 1024 + 2 * h];
        float im = ap[(size_t)n * 1024 + 2 * h + 1];
        float mag = sqrtf(re * re + im * im);
        float s = 1.f / (1.f + __expf(-mag));
        float gr, gi;
        if (mag < 1e-30f) { gr = s; gi = 0.f; }
        else { float inv = s / mag; gr = re * inv; gi = im * inv; }
        float kv  = k * v;
        float nsr = gr * sr - gi * si + kv;
        float nsi = gr * si + gi * sr;
        op[(size_t)n * 512 + h] = q * nsr;
        sr = nsr; si = nsi;
    }
}

// ---------------------------------------------------------------------------
// Elementwise: a *= b  (float4)
// ---------------------------------------------------------------------------
__global__ void mul_k(float* __restrict__ a, const float* __restrict__ b) {
    int i = blockIdx.x * blockDim.x + threadIdx.x;
    float4 av = ((const float4*)a)[i];
    float4 bv = ((const float4*)b)[i];
    ((float4*)a)[i] = make_float4(av.x * bv.x, av.y * bv.y, av.z * bv.z, av.w * bv.w);
}

// ---------------------------------------------------------------------------
extern "C" void kernel_launch(void* const* d_in, const int* in_sizes, int n_in,
                              void* d_out, int out_size, void* d_ws, size_t ws_size,
                              hipStream_t stream) {
    const int*   tokens      = (const int*)d_in[0];
    const float* emb         = (const float*)d_in[1];
    const float* gamma_attn  = (const float*)d_in[2];
    const float* Wqkv        = (const float*)d_in[3];
    const float* Wa          = (const float*)d_in[4];
    const float* ba          = (const float*)d_in[5];
    const float* Wg          = (const float*)d_in[6];
    const float* Wo          = (const float*)d_in[7];
    const float* gamma_ff    = (const float*)d_in[8];
    const float* W1          = (const float*)d_in[9];
    const float* b1          = (const float*)d_in[10];
    const float* W2          = (const float*)d_in[11];
    const float* b2          = (const float*)d_in[12];
    const float* gamma_final = (const float*)d_in[13];
    const float* Wl          = (const float*)d_in[14];
    float* out = (float*)d_out;

    float* ws = (float*)d_ws;
    float* x     = ws;                      // 1M floats [2048,512]
    float* h     = ws + (1u << 20);         // 1M
    float* buf   = ws + (2u << 20);         // 4M (qkv [2048,1536] / ff1 [2048,2048])
    float* ab    = ws + (6u << 20);         // 2M [2048,1024]
    float* attn  = ws + (8u << 20);         // 1M [2048,512]
    float* gated = ws + (9u << 20);         // 1M [2048,512]

    gather_embed<<<M_TOK, 128, 0, stream>>>(tokens, emb, x);

    for (int l = 0; l < DEPTH; l++) {
        // --- attention block ---
        rmsnorm_k<<<512, 256, 0, stream>>>(x, gamma_attn + l * DIM, h);
        sgemm<0><<<dim3(1536 / 64, M_TOK / 64), 256, 0, stream>>>(
            h, Wqkv + (size_t)l * DIM * 1536, nullptr, nullptr, buf, M_TOK, 1536, DIM);
        sgemm<0><<<dim3(1024 / 64, M_TOK / 64), 256, 0, stream>>>(
            h, Wa + (size_t)l * DIM * 1024, ba + (size_t)l * 1024, nullptr, ab, M_TOK, 1024, DIM);
        sgemm<2><<<dim3(512 / 64, M_TOK / 64), 256, 0, stream>>>(
            h, Wg + (size_t)l * DIM * DIM, nullptr, nullptr, gated, M_TOK, 512, DIM);
        scan_attn<<<16, 64, 0, stream>>>(buf, ab, attn);
        mul_k<<<(M_TOK * DIM / 4) / 256, 256, 0, stream>>>(gated, attn);
        sgemm<0><<<dim3(512 / 64, M_TOK / 64), 256, 0, stream>>>(
            gated, Wo + (size_t)l * DIM * DIM, nullptr, x, x, M_TOK, 512, DIM);

        // --- FF block ---
        rmsnorm_k<<<512, 256, 0, stream>>>(x, gamma_ff + l * DIM, h);
        sgemm<1><<<dim3(FF_DIM / 64, M_TOK / 64), 256, 0, stream>>>(
            h, W1 + (size_t)l * DIM * FF_DIM, b1 + (size_t)l * FF_DIM, nullptr, buf, M_TOK, FF_DIM, DIM);
        sgemm<0><<<dim3(512 / 64, M_TOK / 64), 256, 0, stream>>>(
            buf, W2 + (size_t)l * FF_DIM * DIM, b2 + (size_t)l * DIM, x, x, M_TOK, 512, FF_DIM);
    }

    // --- final norm + LM head ---
    rmsnorm_k<<<512, 256, 0, stream>>>(x, gamma_final, h);
    sgemm<0><<<dim3(VOCAB / 64, M_TOK / 64), 256, 0, stream>>>(
        h, Wl, nullptr, nullptr, out, M_TOK, VOCAB, DIM);
}

// Round 3
// 2632.623 us; speedup vs baseline: 1.6622x; 1.6622x over previous
//
#include <hip/hip_runtime.h>
#include <hip/hip_bf16.h>
#include <math.h>

#define DIM 512
#define DEPTH 4
#define VOCAB 32000
#define FF_DIM 2048
#define NB 2
#define NN 1024
#define M_TOK (NB * NN)   // 2048 token rows

typedef __attribute__((ext_vector_type(8))) short short8;
typedef __attribute__((ext_vector_type(4))) float f32x4;

// round-to-nearest-even fp32 -> bf16 bit pattern
__device__ __forceinline__ unsigned short f2bf(float f) {
    union { float f; unsigned u; } v; v.f = f;
    unsigned r = v.u + 0x7FFF + ((v.u >> 16) & 1);
    return (unsigned short)(r >> 16);
}

__device__ __forceinline__ float gelu_f(float v) {
    return 0.5f * v * (1.f + erff(v * 0.7071067811865476f));
}
__device__ __forceinline__ float silu_f(float v) {
    return v / (1.f + __expf(-v));
}

// ---------------------------------------------------------------------------
// Embedding gather: x[t,:] = emb[tokens[t],:]
// ---------------------------------------------------------------------------
__global__ void gather_embed(const int* __restrict__ tok,
                             const float* __restrict__ emb,
                             float* __restrict__ x) {
    int t = blockIdx.x;
    int c = threadIdx.x;
    const float4* src = (const float4*)(emb + (size_t)tok[t] * DIM);
    float4* dst = (float4*)(x + (size_t)t * DIM);
    dst[c] = src[c];
}

// ---------------------------------------------------------------------------
// rmsnorm -> bf16 output (GEMM A operand)
// ---------------------------------------------------------------------------
__global__ void rmsnorm_k(const float* __restrict__ x,
                          const float* __restrict__ gamma,
                          unsigned short* __restrict__ y) {
    int wave = threadIdx.x >> 6;
    int lane = threadIdx.x & 63;
    int row  = blockIdx.x * 4 + wave;
    const float* xr = x + (size_t)row * DIM;
    float vals[8];
    float ss = 0.f;
#pragma unroll
    for (int i = 0; i < 8; i++) {
        vals[i] = xr[lane + i * 64];
        ss += vals[i] * vals[i];
    }
#pragma unroll
    for (int o = 32; o; o >>= 1) ss += __shfl_xor(ss, o, 64);
    float norm  = sqrtf(ss);
    float scale = 22.62741699796952f / fmaxf(norm, 1e-12f);  // sqrt(512)
    unsigned short* yr = y + (size_t)row * DIM;
#pragma unroll
    for (int i = 0; i < 8; i++) {
        int c = lane + i * 64;
        yr[c] = f2bf(vals[i] * scale * gamma[c]);
    }
}

// ---------------------------------------------------------------------------
// Weight convert + transpose: fp32 W[K][N] -> bf16 Wt[N][K].
// One launch handles all 4 layers' weights + Wl. 64x64 tiles, 256 threads.
// ---------------------------------------------------------------------------
__device__ __forceinline__ void transpose_tile(const float* __restrict__ W,
                                               unsigned short* __restrict__ Wt,
                                               int K, int N, int tile) {
    __shared__ float t[64][65];
    int nx = N >> 6;
    int n0 = (tile % nx) << 6, k0 = (tile / nx) << 6;
    int r  = threadIdx.x >> 4, c4 = (threadIdx.x & 15) << 2;
#pragma unroll
    for (int i = 0; i < 4; i++) {
        int kk = r + i * 16;
        float4 v = *(const float4*)&W[(size_t)(k0 + kk) * N + n0 + c4];
        t[kk][c4 + 0] = v.x; t[kk][c4 + 1] = v.y;
        t[kk][c4 + 2] = v.z; t[kk][c4 + 3] = v.w;
    }
    __syncthreads();
#pragma unroll
    for (int i = 0; i < 4; i++) {
        int nn = r + i * 16;
        ushort4 pk;
        pk.x = f2bf(t[c4 + 0][nn]);
        pk.y = f2bf(t[c4 + 1][nn]);
        pk.z = f2bf(t[c4 + 2][nn]);
        pk.w = f2bf(t[c4 + 3][nn]);
        *(ushort4*)&Wt[(size_t)(n0 + nn) * K + k0 + c4] = pk;
    }
}

// grid: 4 layers * 960 tiles + 4000 tiles (Wl) = 7840 blocks
__global__ __launch_bounds__(256)
void conv_all(const float* __restrict__ Wqkv, const float* __restrict__ Wa,
              const float* __restrict__ Wg,   const float* __restrict__ Wo,
              const float* __restrict__ W1,   const float* __restrict__ W2,
              const float* __restrict__ Wl,
              unsigned short* Wq_t, unsigned short* Wa_t, unsigned short* Wg_t,
              unsigned short* Wo_t, unsigned short* W1_t, unsigned short* W2_t,
              unsigned short* Wl_t) {
    int b = blockIdx.x;
    if (b < 3840) {
        int l = b / 960, r = b % 960;
        const float* W; unsigned short* Wt; int K, N, t;
        if (r < 192)      { W = Wqkv + (size_t)l * 512 * 1536; Wt = Wq_t + (size_t)l * 1536 * 512; K = 512;  N = 1536; t = r; }
        else if (r < 320) { W = Wa  + (size_t)l * 512 * 1024; Wt = Wa_t + (size_t)l * 1024 * 512; K = 512;  N = 1024; t = r - 192; }
        else if (r < 384) { W = Wg  + (size_t)l * 512 * 512;  Wt = Wg_t + (size_t)l * 512 * 512;  K = 512;  N = 512;  t = r - 320; }
        else if (r < 448) { W = Wo  + (size_t)l * 512 * 512;  Wt = Wo_t + (size_t)l * 512 * 512;  K = 512;  N = 512;  t = r - 384; }
        else if (r < 704) { W = W1  + (size_t)l * 512 * 2048; Wt = W1_t + (size_t)l * 2048 * 512; K = 512;  N = 2048; t = r - 448; }
        else              { W = W2  + (size_t)l * 2048 * 512; Wt = W2_t + (size_t)l * 512 * 2048; K = 2048; N = 512;  t = r - 704; }
        transpose_tile(W, Wt, K, N, t);
    } else {
        transpose_tile(Wl, Wl_t, 512, 32000, b - 3840);
    }
}

// ---------------------------------------------------------------------------
// bf16 MFMA GEMM (m97 structure): C[M,N] = act(A[M,K] @ Bt[N,K]^T + bias) (+resid)
// 128x128 tile, BK=64, 256 threads = 4 waves (2x2), 4x4 16x16 frags per wave.
// global_load_lds(16B) into linear LDS with pre-swizzled global source;
// swizzled ds_read_b128 on the way out (T2: byte ^= (row&7)<<4).
// ---------------------------------------------------------------------------
typedef const __attribute__((address_space(1))) void* gas1;
typedef __attribute__((address_space(3))) void* as3;

__device__ __forceinline__ void gl_lds16(const void* g, void* l) {
    __builtin_amdgcn_global_load_lds((gas1)g, (as3)l, 16, 0, 0);
}

template <int ACT, int BIAS, int RESID, int OUTF, int OUTB>
__global__ __launch_bounds__(256)
void bgemm(const unsigned short* __restrict__ A,   // [M,K] bf16
           const unsigned short* __restrict__ Bt,  // [N,K] bf16
           const float* __restrict__ bias,
           const float* __restrict__ resid,
           float* __restrict__ Cf,
           unsigned short* __restrict__ Cb,
           int M, int N, int K) {
    __shared__ char smem[32768];
    char* sA = smem;
    char* sB = smem + 16384;
    const int tid  = threadIdx.x;
    const int wv   = tid >> 6, lane = tid & 63;
    const int wm   = wv >> 1,  wn   = wv & 1;
    const int bm   = blockIdx.y * 128, bn = blockIdx.x * 128;
    const int srow = lane >> 3;           // + chunk*8
    const int scol = (lane & 7) * 16;
    const size_t lda = (size_t)K * 2;     // bytes
    const char* Ab = (const char*)A;
    const char* Bb = (const char*)Bt;

    f32x4 acc[4][4];
#pragma unroll
    for (int m = 0; m < 4; m++)
#pragma unroll
        for (int n = 0; n < 4; n++)
            acc[m][n] = (f32x4){0.f, 0.f, 0.f, 0.f};

    for (int k0 = 0; k0 < K; k0 += 64) {
#pragma unroll
        for (int i = 0; i < 4; i++) {
            int chunk = wv * 4 + i;
            int row   = chunk * 8 + srow;
            int sc    = scol ^ ((row & 7) << 4);
            gl_lds16(Ab + (size_t)(bm + row) * lda + k0 * 2 + sc, sA + chunk * 1024);
            gl_lds16(Bb + (size_t)(bn + row) * lda + k0 * 2 + sc, sB + chunk * 1024);
        }
        __syncthreads();
#pragma unroll
        for (int kk = 0; kk < 2; kk++) {
            short8 af[4], bfr[4];
            int kb = kk * 64 + (lane >> 4) * 16;
#pragma unroll
            for (int m = 0; m < 4; m++) {
                int r = wm * 64 + m * 16 + (lane & 15);
                af[m] = *(const short8*)(sA + ((r * 128 + kb) ^ ((r & 7) << 4)));
            }
#pragma unroll
            for (int n = 0; n < 4; n++) {
                int r = wn * 64 + n * 16 + (lane & 15);
                bfr[n] = *(const short8*)(sB + ((r * 128 + kb) ^ ((r & 7) << 4)));
            }
#pragma unroll
            for (int m = 0; m < 4; m++)
#pragma unroll
                for (int n = 0; n < 4; n++)
                    acc[m][n] = __builtin_amdgcn_mfma_f32_16x16x32_bf16(af[m], bfr[n], acc[m][n], 0, 0, 0);
        }
        __syncthreads();
    }

#pragma unroll
    for (int m = 0; m < 4; m++) {
        int row0 = bm + wm * 64 + m * 16 + (lane >> 4) * 4;
#pragma unroll
        for (int n = 0; n < 4; n++) {
            int col = bn + wn * 64 + n * 16 + (lane & 15);
            float bv = BIAS ? bias[col] : 0.f;
#pragma unroll
            for (int j = 0; j < 4; j++) {
                int row = row0 + j;
                float v = acc[m][n][j] + bv;
                if (ACT == 1) v = gelu_f(v);
                else if (ACT == 2) v = silu_f(v);
                if (RESID) v += resid[(size_t)row * N + col];
                if (OUTF) Cf[(size_t)row * N + col] = v;
                if (OUTB) Cb[(size_t)row * N + col] = f2bf(v);
            }
        }
    }
}

// ---------------------------------------------------------------------------
// Gate-loop scan (fp32): one thread per (b, head); DH=1 complex scalar state.
// ---------------------------------------------------------------------------
__global__ void scan_attn(const float* __restrict__ qkv,
                          const float* __restrict__ abuf,
                          float* __restrict__ out) {
    int t = blockIdx.x * 64 + threadIdx.x;   // 0..1023
    int b = t >> 9, h = t & 511;
    const float* qk = qkv + (size_t)b * NN * 1536;
    const float* ap = abuf + (size_t)b * NN * 1024;
    float* op = out + (size_t)b * NN * 512;
    float sr = 0.f, si = 0.f;
#pragma unroll 4
    for (int n = 0; n < NN; n++) {
        float q  = qk[(size_t)n * 1536 + h];
        float k  = qk[(size_t)n * 1536 + 512 + h];
        float v  = qk[(size_t)n * 1536 + 1024 + h];
        float re = ap[(size_t)n * 1024 + 2 * h];
        float im = ap[(size_t)n * 1024 + 2 * h + 1];
        float mag = sqrtf(re * re + im * im);
        float s = 1.f / (1.f + __expf(-mag));
        float gr, gi;
        if (mag < 1e-30f) { gr = s; gi = 0.f; }
        else { float inv = s / mag; gr = re * inv; gi = im * inv; }
        float kv  = k * v;
        float nsr = gr * sr - gi * si + kv;
        float nsi = gr * si + gi * sr;
        op[(size_t)n * 512 + h] = q * nsr;
        sr = nsr; si = nsi;
    }
}

// ---------------------------------------------------------------------------
// gated(f32, silu applied) * attn(f32) -> bf16 (A operand of Wo GEMM)
// ---------------------------------------------------------------------------
__global__ void mulbf_k(const float* __restrict__ a, const float* __restrict__ b,
                        unsigned short* __restrict__ o) {
    int i = blockIdx.x * blockDim.x + threadIdx.x;
    float4 av = ((const float4*)a)[i];
    float4 bv = ((const float4*)b)[i];
    ushort4 pk;
    pk.x = f2bf(av.x * bv.x); pk.y = f2bf(av.y * bv.y);
    pk.z = f2bf(av.z * bv.z); pk.w = f2bf(av.w * bv.w);
    ((ushort4*)o)[i] = pk;
}

// ---------------------------------------------------------------------------
extern "C" void kernel_launch(void* const* d_in, const int* in_sizes, int n_in,
                              void* d_out, int out_size, void* d_ws, size_t ws_size,
                              hipStream_t stream) {
    const int*   tokens      = (const int*)d_in[0];
    const float* emb         = (const float*)d_in[1];
    const float* gamma_attn  = (const float*)d_in[2];
    const float* Wqkv        = (const float*)d_in[3];
    const float* Wa          = (const float*)d_in[4];
    const float* ba          = (const float*)d_in[5];
    const float* Wg          = (const float*)d_in[6];
    const float* Wo          = (const float*)d_in[7];
    const float* gamma_ff    = (const float*)d_in[8];
    const float* W1          = (const float*)d_in[9];
    const float* b1          = (const float*)d_in[10];
    const float* W2          = (const float*)d_in[11];
    const float* b2          = (const float*)d_in[12];
    const float* gamma_final = (const float*)d_in[13];
    const float* Wl          = (const float*)d_in[14];
    float* out = (float*)d_out;

    const size_t MiB = 1u << 20;
    // d_ws: only first 40 MiB known-safe. x(4) + h(2) + Wl_t(31.25) = 37.25 MiB
    char* wsb = (char*)d_ws;
    float*          x    = (float*)(wsb);
    unsigned short* h    = (unsigned short*)(wsb + 4 * MiB);
    unsigned short* Wl_t = (unsigned short*)(wsb + 6 * MiB);

    // d_out (250 MiB) doubles as scratch; final GEMM (reads only d_ws) overwrites it all.
    char* ob = (char*)d_out;
    float*          qkv   = (float*)(ob);              // 12 MiB  [2048,1536]
    float*          abuf  = (float*)(ob + 12 * MiB);   // 8 MiB   [2048,1024]
    float*          attn  = (float*)(ob + 20 * MiB);   // 4 MiB   [2048,512]
    float*          gated = (float*)(ob + 24 * MiB);   // 4 MiB   [2048,512]
    unsigned short* gbf   = (unsigned short*)(ob + 28 * MiB);  // 2 MiB
    unsigned short* ff1   = (unsigned short*)(ob + 30 * MiB);  // 8 MiB [2048,2048]
    unsigned short* Wq_t  = (unsigned short*)(ob + 38 * MiB);  // 6 MiB
    unsigned short* Wa_t  = (unsigned short*)(ob + 44 * MiB);  // 4 MiB
    unsigned short* Wg_t  = (unsigned short*)(ob + 48 * MiB);  // 2 MiB
    unsigned short* Wo_t  = (unsigned short*)(ob + 50 * MiB);  // 2 MiB
    unsigned short* W1_t  = (unsigned short*)(ob + 52 * MiB);  // 8 MiB
    unsigned short* W2_t  = (unsigned short*)(ob + 60 * MiB);  // 8 MiB

    conv_all<<<7840, 256, 0, stream>>>(Wqkv, Wa, Wg, Wo, W1, W2, Wl,
                                       Wq_t, Wa_t, Wg_t, Wo_t, W1_t, W2_t, Wl_t);
    gather_embed<<<M_TOK, 128, 0, stream>>>(tokens, emb, x);

    for (int l = 0; l < DEPTH; l++) {
        rmsnorm_k<<<512, 256, 0, stream>>>(x, gamma_attn + l * DIM, h);
        bgemm<0,0,0,1,0><<<dim3(1536/128, 16), 256, 0, stream>>>(
            h, Wq_t + (size_t)l * 1536 * 512, nullptr, nullptr, qkv, nullptr, M_TOK, 1536, 512);
        bgemm<0,1,0,1,0><<<dim3(1024/128, 16), 256, 0, stream>>>(
            h, Wa_t + (size_t)l * 1024 * 512, ba + (size_t)l * 1024, nullptr, abuf, nullptr, M_TOK, 1024, 512);
        bgemm<2,0,0,1,0><<<dim3(512/128, 16), 256, 0, stream>>>(
            h, Wg_t + (size_t)l * 512 * 512, nullptr, nullptr, gated, nullptr, M_TOK, 512, 512);
        scan_attn<<<16, 64, 0, stream>>>(qkv, abuf, attn);
        mulbf_k<<<(M_TOK * DIM / 4) / 256, 256, 0, stream>>>(gated, attn, gbf);
        bgemm<0,0,1,1,0><<<dim3(512/128, 16), 256, 0, stream>>>(
            gbf, Wo_t + (size_t)l * 512 * 512, nullptr, x, x, nullptr, M_TOK, 512, 512);

        rmsnorm_k<<<512, 256, 0, stream>>>(x, gamma_ff + l * DIM, h);
        bgemm<1,1,0,0,1><<<dim3(2048/128, 16), 256, 0, stream>>>(
            h, W1_t + (size_t)l * 2048 * 512, b1 + (size_t)l * FF_DIM, nullptr, nullptr, ff1, M_TOK, 2048, 512);
        bgemm<0,1,1,1,0><<<dim3(512/128, 16), 256, 0, stream>>>(
            ff1, W2_t + (size_t)l * 512 * 2048, b2 + (size_t)l * DIM, x, x, nullptr, M_TOK, 512, 2048);
    }

    rmsnorm_k<<<512, 256, 0, stream>>>(x, gamma_final, h);
    bgemm<0,0,0,1,0><<<dim3(VOCAB/128, 16), 256, 0, stream>>>(
        h, Wl_t, nullptr, nullptr, out, nullptr, M_TOK, VOCAB, 512);
}